// Round 11
// baseline (282.657 us; speedup 1.0000x reference)
//
#include <hip/hip_runtime.h>

// Caps_BN: BatchNorm2d (training stats, affine=False) + grouped 1x1 conv
// (16 capsules of 32x32) + bias. x (64, 512, 32, 32) f32.
//
// SINGLE fused kernel with PER-CAPSULE producer->consumer sync (no grid barrier):
//   blocks 0..511   : stats for channel ch=b (mean, rstd) -> atomic release-add
//                     to cnt[ch>>5] (16 counters, 512 RMWs total).
//   blocks 512..4607: main tile; spin on ATOMIC LOAD of cnt[c] (no RMW polling
//                     -- R9's 500us lesson), normalize xv in registers with
//                     mean/rstd, then out = w @ xn + bias (raw w on scalar path;
//                     the fold kernel is eliminated entirely).
// Deadlock-free by construction: consumers only wait on blocks dispatched
// EARLIER (CP places blocks in order), spins are bounded, bar_init re-zeroes
// counters every launch so graph replays are deterministic.
//
// Lessons encoded:
//  - R8: cooperative grid.sync is not graph-capture-safe. R9: atomicAdd POLLING
//    serializes the fabric (~500us). Poll with __hip_atomic_load only.
//  - NEVER set launch_bounds min-waves: forced VGPR=40 + scratch spill twice
//    (R4, R6). Plain __launch_bounds__(256) = VGPR 52 clean.
//  - xv[32] + 4 independent partials = proven spill-free ILP shape (R5).
//  - scalar 4B/lane stores = exactly 1.0x WRITE_SIZE; nt stores + L3-resident x
//    give FETCH == one x read for the whole fused pipeline (R6/R9: 131.7 MB).
//  - R10: cross-quarter prefetch is VGPR-neutral-negative; don't.

#define NELEM_PER_CH 65536.0f
#define WS_CNT 17920   // 16 ints (capsule arrival counters) at float offset 17920

__global__ void bar_init(int* __restrict__ cnt) {
    if (threadIdx.x < 16) cnt[threadIdx.x] = 0;
}

__global__ __launch_bounds__(256) void caps_fused(const float* __restrict__ x,
                                                  const float* __restrict__ w,
                                                  const float* __restrict__ bias,
                                                  float* __restrict__ out,
                                                  float* __restrict__ ws,
                                                  int* __restrict__ cnt) {
    const int b = blockIdx.x;
    const int t = threadIdx.x;

    __shared__ float red[4][2];
    __shared__ float smean[32], srstd[32];

    if (b < 512) {
        // ---------------- stats block: channel ch = b ----------------
        const int ch = b;
        const float4* __restrict__ x4 = (const float4*)x;
        float s = 0.f, ss = 0.f;
#pragma unroll 4
        for (int n = 0; n < 64; ++n) {
            float4 v = x4[((size_t)n * 512 + ch) * 256 + t];
            s  += v.x + v.y + v.z + v.w;
            ss += v.x * v.x + v.y * v.y + v.z * v.z + v.w * v.w;
        }
#pragma unroll
        for (int off = 32; off > 0; off >>= 1) {
            s  += __shfl_down(s, off);
            ss += __shfl_down(ss, off);
        }
        if ((t & 63) == 0) { red[t >> 6][0] = s; red[t >> 6][1] = ss; }
        __syncthreads();
        if (t == 0) {
            float S = 0.f, SS = 0.f;
#pragma unroll
            for (int k = 0; k < 4; ++k) { S += red[k][0]; SS += red[k][1]; }
            const float mean = S / NELEM_PER_CH;
            const float rstd = rsqrtf(SS / NELEM_PER_CH - mean * mean + 1e-5f);
            __hip_atomic_store(&ws[ch], mean, __ATOMIC_RELAXED,
                               __HIP_MEMORY_SCOPE_AGENT);
            __hip_atomic_store(&ws[512 + ch], rstd, __ATOMIC_RELAXED,
                               __HIP_MEMORY_SCOPE_AGENT);
            __hip_atomic_fetch_add(&cnt[ch >> 5], 1, __ATOMIC_RELEASE,
                                   __HIP_MEMORY_SCOPE_AGENT);
        }
        return;
    }

    // ---------------- main block: tile m = b - 512 ----------------
    const int m = b - 512;          // 0..4095, capsule-major
    const int c = m >> 8;           // 256 tiles per capsule
    const int n = (m >> 2) & 63;
    const int q = m & 3;

    // wait until this capsule's 32 channel-stats have been published
    if (t == 0) {
        int spins = 0;
        while (__hip_atomic_load(&cnt[c], __ATOMIC_ACQUIRE,
                                 __HIP_MEMORY_SCOPE_AGENT) < 32 &&
               spins < (1 << 20)) {
            ++spins;
            __builtin_amdgcn_s_sleep(16);
        }
    }
    __syncthreads();
    if (t < 32) {
        smean[t] = __hip_atomic_load(&ws[c * 32 + t], __ATOMIC_RELAXED,
                                     __HIP_MEMORY_SCOPE_AGENT);
        srstd[t] = __hip_atomic_load(&ws[512 + c * 32 + t], __ATOMIC_RELAXED,
                                     __HIP_MEMORY_SCOPE_AGENT);
    }
    __syncthreads();

    const size_t base = (((size_t)n * 16 + c) * 32) * 1024 + q * 256 + t;
    const float* __restrict__ Wc = w + c * 1024;        // raw weight, block-uniform
    const float* __restrict__ bp = bias + c * 32;

    float xv[32];
#pragma unroll
    for (int i = 0; i < 32; ++i)
        xv[i] = (x[base + (size_t)i * 1024] - smean[i]) * srstd[i];

#pragma unroll 4
    for (int o = 0; o < 32; ++o) {
        const float* __restrict__ wr = Wc + o * 32;     // s_load rows (const input)
        float p0 = bp[o], p1 = 0.f, p2 = 0.f, p3 = 0.f;
#pragma unroll
        for (int i = 0; i < 32; i += 4) {
            p0 += wr[i + 0] * xv[i + 0];
            p1 += wr[i + 1] * xv[i + 1];
            p2 += wr[i + 2] * xv[i + 2];
            p3 += wr[i + 3] * xv[i + 3];
        }
        __builtin_nontemporal_store(((p0 + p1) + (p2 + p3)),
                                    out + base + (size_t)o * 1024);
    }
}

extern "C" void kernel_launch(void* const* d_in, const int* in_sizes, int n_in,
                              void* d_out, int out_size, void* d_ws, size_t ws_size,
                              hipStream_t stream) {
    const float* x    = (const float*)d_in[0];
    const float* w    = (const float*)d_in[1];
    const float* bias = (const float*)d_in[2];
    float* out = (float*)d_out;
    float* ws  = (float*)d_ws;
    int* cnt   = (int*)(ws + WS_CNT);

    bar_init<<<1, 64, 0, stream>>>(cnt);
    caps_fused<<<512 + 4096, 256, 0, stream>>>(x, w, bias, out, ws, cnt);
}